// Round 6
// baseline (524.521 us; speedup 1.0000x reference)
//
#include <hip/hip_runtime.h>

typedef __attribute__((ext_vector_type(4))) float  float4_;
typedef __attribute__((ext_vector_type(8))) short  short8;
typedef __attribute__((ext_vector_type(8))) __bf16 bf16x8;

__device__ inline unsigned short f2bf(float f) {
    unsigned u = __builtin_bit_cast(unsigned, f);
    u += 0x7FFFu + ((u >> 16) & 1u);          // round-to-nearest-even
    return (unsigned short)(u >> 16);
}

__device__ inline float4_ mfma16(bf16x8 a, bf16x8 b, float4_ c) {
    return __builtin_amdgcn_mfma_f32_16x16x32_bf16(a, b, c, 0, 0, 0);
}

// ---------------- one merged setup kernel ----------------
// packs all weights into B-fragment order + zeroes sentinel row cat[N].
// Conv weight tables now have 28 slots: slot 27 is ALL-ZERO (branchless
// conv points inactive slots here; mfma x 0 == 0).
// frag f = (k*ctn + ct)*ntn + nt ; elem = lane*8 + t
// value = W[k][ct*32 + (lane>>4)*8 + t][nt*16 + (lane&15)]
__device__ inline void packW_one(const float* __restrict__ src, unsigned short* __restrict__ dst,
                                 int cin, int cout, int e) {
    int f = e >> 9, i = e & 511, lane = i >> 3, t = i & 7;
    int ntn = cout >> 4, ctn = cin >> 5;
    int nt = f % ntn;
    int rest = f / ntn;
    int ct = rest % ctn;
    int k = rest / ctn;
    int c = ct * 32 + (lane >> 4) * 8 + t;
    int j = nt * 16 + (lane & 15);
    dst[e] = f2bf(src[(k * cin + c) * cout + j]);
}

__global__ void pack_all_kernel(
    const float* __restrict__ W1, const float* __restrict__ W2,
    const float* __restrict__ W3, const float* __restrict__ W4,
    const float* __restrict__ W5, const float* __restrict__ W6,
    const float* __restrict__ W7,
    unsigned short* cat, unsigned short* Wp12, unsigned short* Wp3,
    unsigned short* Wp4, unsigned short* Wp5, unsigned short* Wp6,
    unsigned short* Wp7, int N) {
    int e = blockIdx.x * 256 + threadIdx.x;
    if (e < 8192) {                                  // W1|W2 -> (64,128)
        int f = e >> 9, i = e & 511, lane = i >> 3, t = i & 7;
        int nt = f & 7, ct = f >> 3;
        int c = ct * 32 + (lane >> 4) * 8 + t;
        int j = nt * 16 + (lane & 15);
        float v = (j < 64) ? W1[c * 64 + j] : W2[c * 64 + (j - 64)];
        Wp12[e] = f2bf(v);
        return;
    }
    e -= 8192;
    if (e < 57344) { if (e < 55296) packW_one(W3, Wp3, 64, 32, e); else Wp3[e] = 0; return; }
    e -= 57344;
    if (e < 28672) { if (e < 27648) packW_one(W4, Wp4, 32, 32, e); else Wp4[e] = 0; return; }
    e -= 28672;
    if (e < 28672) { if (e < 27648) packW_one(W5, Wp5, 32, 32, e); else Wp5[e] = 0; return; }
    e -= 28672;
    if (e < 28672) { if (e < 27648) packW_one(W6, Wp6, 32, 32, e); else Wp6[e] = 0; return; }
    e -= 28672;
    if (e < 16384) { packW_one(W7, Wp7, 256, 64, e); return; }
    e -= 16384;
    if (e < 128) ((unsigned*)(cat + (size_t)N * 256))[e] = 0;   // sentinel row
}

// ---------------- plan kernel v3: masks + COMPACTED index table ----------
// Coalesced read of nbr into LDS; per 16-row tile t emits:
//   kmask[t]            union mask of valid taps
//   cidx[t][j][r]       neighbor row of row r for the j-th ACTIVE tap
//                       (ascending k; invalid row -> N). 64B per (t,j):
//                       conv reads it as ONE coalesced line per slot.
__global__ __launch_bounds__(256) void plan_kernel(const int* __restrict__ nbr,
                                                   unsigned int* __restrict__ kmask,
                                                   int* __restrict__ cidx, int N) {
    __shared__ int snb[6912];                        // 256 rows * 27 taps
    __shared__ unsigned tm[16];
    int tid = threadIdx.x;
    if (tid < 16) tm[tid] = 0u;
    __syncthreads();
    long base = (long)blockIdx.x * 6912;
#pragma unroll
    for (int i = 0; i < 27; i++) {
        int j = i * 256 + tid;
        int v = nbr[base + j];
        snb[j] = v;
        if (v >= 0) {
            unsigned r = (unsigned)j / 27u;          // local row 0..255
            unsigned k = (unsigned)j - r * 27u;
            atomicOr(&tm[r >> 4], 1u << k);
        }
    }
    __syncthreads();
    int g = tid >> 4, r = tid & 15;                  // 16 groups x 16 rows
    unsigned m = tm[g];
    int t = blockIdx.x * 16 + g;
    int* cp = cidx + (long)t * 432;
    int j = 0;
#pragma unroll
    for (int k = 0; k < 27; k++) {
        if (m >> k & 1u) {
            int v = snb[(g * 16 + r) * 27 + k];
            cp[j * 16 + r] = (v < 0) ? N : v;
            j++;
        }
    }
    if (r == 0) kmask[t] = m;
}

// ---------------- blk1 dual: f1|f2 = relu(LN(x@W + b)) ----------------
__global__ __launch_bounds__(256) void blk12_kernel(
    const float* __restrict__ x, unsigned short* cat,
    const unsigned short* __restrict__ Wp,
    const float* __restrict__ b1, const float* __restrict__ g1, const float* __restrict__ be1,
    const float* __restrict__ b2, const float* __restrict__ g2, const float* __restrict__ be2) {
    int tid = threadIdx.x, lane = tid & 63, wv = tid >> 6;
    int l15 = lane & 15, q = lane >> 4;
    long base = ((long)blockIdx.x * 4 + wv) * 16;

    float4_ acc[8];
#pragma unroll
    for (int i = 0; i < 8; i++) acc[i] = (float4_){0.f, 0.f, 0.f, 0.f};

#pragma unroll
    for (int kt = 0; kt < 2; kt++) {
        const float* xp = x + (base + l15) * 64 + kt * 32 + q * 8;
        float4_ f0 = *(const float4_*)xp;
        float4_ f1 = *(const float4_*)(xp + 4);
        short8 as;
        as[0] = (short)f2bf(f0[0]); as[1] = (short)f2bf(f0[1]);
        as[2] = (short)f2bf(f0[2]); as[3] = (short)f2bf(f0[3]);
        as[4] = (short)f2bf(f1[0]); as[5] = (short)f2bf(f1[1]);
        as[6] = (short)f2bf(f1[2]); as[7] = (short)f2bf(f1[3]);
        bf16x8 a = __builtin_bit_cast(bf16x8, as);
        const unsigned short* wp = Wp + (size_t)kt * 8 * 512;
#pragma unroll
        for (int nt = 0; nt < 8; nt++) {
            bf16x8 w = *(const bf16x8*)(wp + nt * 512 + lane * 8);
            acc[nt] = mfma16(a, w, acc[nt]);
        }
    }

    float bc[8], gc[8], bec[8];
#pragma unroll
    for (int nt = 0; nt < 8; nt++) {
        int j = nt * 16 + l15;
        if (j < 64) { bc[nt] = b1[j]; gc[nt] = g1[j]; bec[nt] = be1[j]; }
        else        { bc[nt] = b2[j - 64]; gc[nt] = g2[j - 64]; bec[nt] = be2[j - 64]; }
    }

#pragma unroll
    for (int r = 0; r < 4; r++) {
        long row = base + q * 4 + r;
        float v[8], s0 = 0.f, s1 = 0.f, q0 = 0.f, q1 = 0.f;
#pragma unroll
        for (int nt = 0; nt < 4; nt++) { v[nt] = acc[nt][r] + bc[nt]; s0 += v[nt]; q0 += v[nt] * v[nt]; }
#pragma unroll
        for (int nt = 4; nt < 8; nt++) { v[nt] = acc[nt][r] + bc[nt]; s1 += v[nt]; q1 += v[nt] * v[nt]; }
#pragma unroll
        for (int m = 1; m < 16; m <<= 1) {
            s0 += __shfl_xor(s0, m); q0 += __shfl_xor(q0, m);
            s1 += __shfl_xor(s1, m); q1 += __shfl_xor(q1, m);
        }
        float mu0 = s0 * (1.f / 64), var0 = q0 * (1.f / 64) - mu0 * mu0, inv0 = rsqrtf(var0 + 1e-5f);
        float mu1 = s1 * (1.f / 64), var1 = q1 * (1.f / 64) - mu1 * mu1, inv1 = rsqrtf(var1 + 1e-5f);
        unsigned short* cp = cat + row * 256;
#pragma unroll
        for (int nt = 0; nt < 4; nt++) {
            float y = fmaxf((v[nt] - mu0) * inv0 * gc[nt] + bec[nt], 0.f);
            cp[nt * 16 + l15] = f2bf(y);
        }
#pragma unroll
        for (int nt = 4; nt < 8; nt++) {
            float y = fmaxf((v[nt] - mu1) * inv1 * gc[nt] + bec[nt], 0.f);
            cp[nt * 16 + l15] = f2bf(y);
        }
    }
}

// ---------------- sparse submanifold conv, BRANCHLESS ----------------
// Round-5 lesson: with per-slot scalar branches, pipeline depth did nothing
// (branch joins force conservative vmcnt drains) and strided nbr loads cost
// ~20+ lines each. v6: ZERO branches in the body.
//   - cidx: one coalesced 64B load per slot (compacted by plan).
//   - slots j >= cnt: index garbage is med3-clamped into [0,N] (L1-hot dup
//     gather) and weights come from the all-zero slot 27 -> MFMA adds 0.
//   - ke[j] = j-th set bit (scalar ctz chain, static unroll) or 27.
// Static rings, static indices, counted vmcnt can flow across all 27 slots.
template <int CT, int D>
__global__ __launch_bounds__(256) void conv_kernel(
    unsigned short* cat, const int* __restrict__ cidx,
    const unsigned int* __restrict__ kmask,
    const unsigned short* __restrict__ Wp,
    const float* __restrict__ bb, const float* __restrict__ gg, const float* __restrict__ bee,
    int in_off, int out_off, int N) {
    int tid = threadIdx.x, lane = tid & 63, wv = tid >> 6;
    int l15 = lane & 15, q = lane >> 4;

    // bijective XCD-chunked swizzle (gridDim.x % 8 == 0)
    int cpx = (int)(gridDim.x >> 3);
    int sb = ((int)blockIdx.x & 7) * cpx + ((int)blockIdx.x >> 3);
    int t = sb * 4 + wv;
    long base = (long)t * 16;

    unsigned m = __builtin_amdgcn_readfirstlane(kmask[t]);

    // slot -> tap map, scalar chain, static unroll (SGPRs)
    int ke[27];
    unsigned mm = m;
#pragma unroll
    for (int j = 0; j < 27; j++) {
        ke[j] = mm ? (int)__builtin_ctz(mm) : 27;    // 27 = zero-weight slot
        mm &= mm - 1u;
    }

    float4_ acc[2];
    acc[0] = (float4_){0.f, 0.f, 0.f, 0.f};
    acc[1] = (float4_){0.f, 0.f, 0.f, 0.f};

    const unsigned short* catp = cat + in_off + q * 8;
    const unsigned short* wl = Wp + lane * 8;
    const int* cx = cidx + (long)t * 432 + l15;

    bf16x8 f[D + 1][CT];
    bf16x8 wr[3][CT][2];
    int ci[3];

    // ---- prologue: cidx slots 0..D+1, weights 0..1, gathers 0..D-1 ----
    int ci0[D + 2];
#pragma unroll
    for (int j = 0; j < D + 2; j++) ci0[j] = cx[j * 16];

#pragma unroll
    for (int kk = 0; kk < 2; kk++)
#pragma unroll
        for (int ct = 0; ct < CT; ct++)
#pragma unroll
            for (int nt = 0; nt < 2; nt++)
                wr[kk][ct][nt] =
                    *(const bf16x8*)(wl + ((size_t)((ke[kk] * CT + ct) * 2 + nt)) * 512);

#pragma unroll
    for (int j = 0; j < D; j++) {
        int v = ci0[j];
        size_t s = (size_t)(v < 0 ? 0 : (v > N ? N : v));   // med3 clamp
#pragma unroll
        for (int ct = 0; ct < CT; ct++)
            f[j][ct] = *(const bf16x8*)(catp + s * 256 + ct * 32);
    }
    ci[D % 3] = ci0[D];
    ci[(D + 1) % 3] = ci0[D + 1];

    // ---- main loop: 27 static slots, no branches ----
#pragma unroll
    for (int k = 0; k < 27; k++) {
        if (k + 2 < 27) {                            // weights for slot k+2
#pragma unroll
            for (int ct = 0; ct < CT; ct++)
#pragma unroll
                for (int nt = 0; nt < 2; nt++)
                    wr[(k + 2) % 3][ct][nt] =
                        *(const bf16x8*)(wl + ((size_t)((ke[k + 2] * CT + ct) * 2 + nt)) * 512);
        }
        if (k + D < 27) {                            // gathers for slot k+D
            int v = ci[(k + D) % 3];
            size_t s = (size_t)(v < 0 ? 0 : (v > N ? N : v));
#pragma unroll
            for (int ct = 0; ct < CT; ct++)
                f[(k + D) % (D + 1)][ct] = *(const bf16x8*)(catp + s * 256 + ct * 32);
        }
        if (k + D + 2 < 27) ci[(k + D + 2) % 3] = cx[(k + D + 2) * 16];
#pragma unroll
        for (int ct = 0; ct < CT; ct++) {            // MFMA for slot k (x0 if inactive)
            acc[0] = mfma16(f[k % (D + 1)][ct], wr[k % 3][ct][0], acc[0]);
            acc[1] = mfma16(f[k % (D + 1)][ct], wr[k % 3][ct][1], acc[1]);
        }
    }

    // ---- epilogue: bias + LN(32ch) + relu + store ----
    float b0c = bb[l15], b1c = bb[16 + l15];
    float g0c = gg[l15], g1c = gg[16 + l15];
    float be0c = bee[l15], be1c = bee[16 + l15];

#pragma unroll
    for (int r = 0; r < 4; r++) {
        long row = base + q * 4 + r;
        float v0 = acc[0][r] + b0c;
        float v1 = acc[1][r] + b1c;
        float s = v0 + v1, sq = v0 * v0 + v1 * v1;
#pragma unroll
        for (int mh = 1; mh < 16; mh <<= 1) { s += __shfl_xor(s, mh); sq += __shfl_xor(sq, mh); }
        float mu = s * (1.f / 32), var = sq * (1.f / 32) - mu * mu, inv = rsqrtf(var + 1e-5f);
        float y0 = fmaxf((v0 - mu) * inv * g0c + be0c, 0.f);
        float y1 = fmaxf((v1 - mu) * inv * g1c + be1c, 0.f);
        unsigned short* cp = cat + row * 256 + out_off;
        cp[l15] = f2bf(y0);
        cp[16 + l15] = f2bf(y1);
    }
}

// ---------------- final blk1: out = relu(LN(cat@W7 + b7)) ----------------
__global__ __launch_bounds__(256) void blk7_kernel(
    const unsigned short* __restrict__ cat, const unsigned short* __restrict__ Wp,
    const float* __restrict__ b, const float* __restrict__ g, const float* __restrict__ be,
    float* __restrict__ out) {
    int tid = threadIdx.x, lane = tid & 63, wv = tid >> 6;
    int l15 = lane & 15, q = lane >> 4;
    long base = ((long)blockIdx.x * 4 + wv) * 16;

    float4_ acc[4];
#pragma unroll
    for (int i = 0; i < 4; i++) acc[i] = (float4_){0.f, 0.f, 0.f, 0.f};

#pragma unroll
    for (int kt = 0; kt < 8; kt++) {
        bf16x8 a = *(const bf16x8*)(cat + (base + l15) * 256 + kt * 32 + q * 8);
        const unsigned short* wp = Wp + (size_t)kt * 4 * 512;
#pragma unroll
        for (int nt = 0; nt < 4; nt++) {
            bf16x8 w = *(const bf16x8*)(wp + nt * 512 + lane * 8);
            acc[nt] = mfma16(a, w, acc[nt]);
        }
    }

    float bc[4], gc[4], bec[4];
#pragma unroll
    for (int nt = 0; nt < 4; nt++) {
        int j = nt * 16 + l15;
        bc[nt] = b[j]; gc[nt] = g[j]; bec[nt] = be[j];
    }

#pragma unroll
    for (int r = 0; r < 4; r++) {
        long row = base + q * 4 + r;
        float v[4], s = 0.f, sq = 0.f;
#pragma unroll
        for (int nt = 0; nt < 4; nt++) { v[nt] = acc[nt][r] + bc[nt]; s += v[nt]; sq += v[nt] * v[nt]; }
#pragma unroll
        for (int m = 1; m < 16; m <<= 1) { s += __shfl_xor(s, m); sq += __shfl_xor(sq, m); }
        float mu = s * (1.f / 64), var = sq * (1.f / 64) - mu * mu, inv = rsqrtf(var + 1e-5f);
#pragma unroll
        for (int nt = 0; nt < 4; nt++) {
            float y = fmaxf((v[nt] - mu) * inv * gc[nt] + bec[nt], 0.f);
            out[row * 64 + nt * 16 + l15] = y;
        }
    }
}

extern "C" void kernel_launch(void* const* d_in, const int* in_sizes, int n_in,
                              void* d_out, int out_size, void* d_ws, size_t ws_size,
                              hipStream_t stream) {
    const int N = in_sizes[0] / 64;   // 262144

    const float* x   = (const float*)d_in[0];
    const int*   nbr = (const int*)d_in[1];
    const float* W1 = (const float*)d_in[2];
    const float* b1 = (const float*)d_in[3];
    const float* g1 = (const float*)d_in[4];
    const float* be1 = (const float*)d_in[5];
    const float* W2 = (const float*)d_in[6];
    const float* b2 = (const float*)d_in[7];
    const float* g2 = (const float*)d_in[8];
    const float* be2 = (const float*)d_in[9];
    const float* W3 = (const float*)d_in[10];
    const float* b3 = (const float*)d_in[11];
    const float* g3 = (const float*)d_in[12];
    const float* be3 = (const float*)d_in[13];
    const float* W4 = (const float*)d_in[14];
    const float* b4 = (const float*)d_in[15];
    const float* g4 = (const float*)d_in[16];
    const float* be4 = (const float*)d_in[17];
    const float* W5 = (const float*)d_in[18];
    const float* b5 = (const float*)d_in[19];
    const float* g5 = (const float*)d_in[20];
    const float* be5 = (const float*)d_in[21];
    const float* W6 = (const float*)d_in[22];
    const float* b6 = (const float*)d_in[23];
    const float* g6 = (const float*)d_in[24];
    const float* be6 = (const float*)d_in[25];
    const float* W7 = (const float*)d_in[26];
    const float* b7 = (const float*)d_in[27];
    const float* g7 = (const float*)d_in[28];
    const float* be7 = (const float*)d_in[29];

    unsigned short* ws   = (unsigned short*)d_ws;
    unsigned short* cat  = ws;                               // (N+1)*256 bf16
    unsigned short* Wp12 = cat + (size_t)(N + 1) * 256;      // 8192
    unsigned short* Wp3  = Wp12 + 8192;                      // 28*2*2*512 = 57344 (slot 27 zero)
    unsigned short* Wp4  = Wp3 + 57344;                      // 28*1*2*512 = 28672
    unsigned short* Wp5  = Wp4 + 28672;
    unsigned short* Wp6  = Wp5 + 28672;
    unsigned short* Wp7  = Wp6 + 28672;                      // 8*4*512 = 16384
    unsigned int*   kmask = (unsigned int*)(Wp7 + 16384);    // N/16 uints
    int*            cidx  = (int*)(kmask + N / 16);          // N/16 * 432 ints

    pack_all_kernel<<<657, 256, 0, stream>>>(W1, W2, W3, W4, W5, W6, W7,
                                             cat, Wp12, Wp3, Wp4, Wp5, Wp6, Wp7, N);
    plan_kernel<<<N / 256, 256, 0, stream>>>(nbr, kmask, cidx, N);

    blk12_kernel<<<N / 64, 256, 0, stream>>>(x, cat, Wp12, b1, g1, be1, b2, g2, be2);
    conv_kernel<2, 3><<<N / 64, 256, 0, stream>>>(cat, cidx, kmask, Wp3, b3, g3, be3, 64, 128, N);
    conv_kernel<1, 4><<<N / 64, 256, 0, stream>>>(cat, cidx, kmask, Wp4, b4, g4, be4, 128, 160, N);
    conv_kernel<1, 4><<<N / 64, 256, 0, stream>>>(cat, cidx, kmask, Wp5, b5, g5, be5, 160, 192, N);
    conv_kernel<1, 4><<<N / 64, 256, 0, stream>>>(cat, cidx, kmask, Wp6, b6, g6, be6, 192, 224, N);
    blk7_kernel<<<N / 64, 256, 0, stream>>>(cat, Wp7, b7, g7, be7, (float*)d_out);
}

// Round 9
// 523.625 us; speedup vs baseline: 1.0017x; 1.0017x over previous
//
#include <hip/hip_runtime.h>

typedef __attribute__((ext_vector_type(4))) float  float4_;
typedef __attribute__((ext_vector_type(8))) short  short8;
typedef __attribute__((ext_vector_type(8))) __bf16 bf16x8;

__device__ inline unsigned short f2bf(float f) {
    unsigned u = __builtin_bit_cast(unsigned, f);
    u += 0x7FFFu + ((u >> 16) & 1u);          // round-to-nearest-even
    return (unsigned short)(u >> 16);
}

__device__ inline float4_ mfma16(bf16x8 a, bf16x8 b, float4_ c) {
    return __builtin_amdgcn_mfma_f32_16x16x32_bf16(a, b, c, 0, 0, 0);
}

// ---------------- one merged setup kernel (r3 layout, 27 slots) ----------
// packs all weights into B-fragment order + zeroes sentinel row cat[N].
// frag f = (k*ctn + ct)*ntn + nt ; elem = lane*8 + t
// value = W[k][ct*32 + (lane>>4)*8 + t][nt*16 + (lane&15)]
__device__ inline void packW_one(const float* __restrict__ src, unsigned short* __restrict__ dst,
                                 int cin, int cout, int e) {
    int f = e >> 9, i = e & 511, lane = i >> 3, t = i & 7;
    int ntn = cout >> 4, ctn = cin >> 5;
    int nt = f % ntn;
    int rest = f / ntn;
    int ct = rest % ctn;
    int k = rest / ctn;
    int c = ct * 32 + (lane >> 4) * 8 + t;
    int j = nt * 16 + (lane & 15);
    dst[e] = f2bf(src[(k * cin + c) * cout + j]);
}

__global__ void pack_all_kernel(
    const float* __restrict__ W1, const float* __restrict__ W2,
    const float* __restrict__ W3, const float* __restrict__ W4,
    const float* __restrict__ W5, const float* __restrict__ W6,
    const float* __restrict__ W7,
    unsigned short* cat, unsigned short* Wp12, unsigned short* Wp3,
    unsigned short* Wp4, unsigned short* Wp5, unsigned short* Wp6,
    unsigned short* Wp7, int N) {
    int e = blockIdx.x * 256 + threadIdx.x;
    if (e < 8192) {                                  // W1|W2 -> (64,128)
        int f = e >> 9, i = e & 511, lane = i >> 3, t = i & 7;
        int nt = f & 7, ct = f >> 3;
        int c = ct * 32 + (lane >> 4) * 8 + t;
        int j = nt * 16 + (lane & 15);
        float v = (j < 64) ? W1[c * 64 + j] : W2[c * 64 + (j - 64)];
        Wp12[e] = f2bf(v);
        return;
    }
    e -= 8192;
    if (e < 55296) { packW_one(W3, Wp3, 64, 32, e); return; }
    e -= 55296;
    if (e < 27648) { packW_one(W4, Wp4, 32, 32, e); return; }
    e -= 27648;
    if (e < 27648) { packW_one(W5, Wp5, 32, 32, e); return; }
    e -= 27648;
    if (e < 27648) { packW_one(W6, Wp6, 32, 32, e); return; }
    e -= 27648;
    if (e < 16384) { packW_one(W7, Wp7, 256, 64, e); return; }
    e -= 16384;
    if (e < 128) ((unsigned*)(cat + (size_t)N * 256))[e] = 0;   // sentinel row
}

// ---------------- plan kernel v4: masks + byte-offset index table --------
// Per 16-row tile t, slot-major cidx[t][k][r] = CLAMPED BYTE OFFSET
// ((v<0?N:v)*512) of row r's neighbor at tap k. Conv reads one coalesced
// 64B line per slot (vs 16-line strided nbr) and does zero clamp math.
__global__ __launch_bounds__(256) void plan_kernel(const int* __restrict__ nbr,
                                                   unsigned int* __restrict__ kmask,
                                                   unsigned int* __restrict__ cidx, int N) {
    __shared__ int snb[6912];                        // 256 rows * 27 taps
    __shared__ unsigned tm[16];
    int tid = threadIdx.x;
    if (tid < 16) tm[tid] = 0u;
    __syncthreads();
    long base = (long)blockIdx.x * 6912;
#pragma unroll
    for (int i = 0; i < 27; i++) {
        int j = i * 256 + tid;
        int v = nbr[base + j];
        snb[j] = v;
        if (v >= 0) {
            unsigned r = (unsigned)j / 27u;          // local row 0..255
            unsigned k = (unsigned)j - r * 27u;
            atomicOr(&tm[r >> 4], 1u << k);
        }
    }
    __syncthreads();
    int g = tid >> 4, r = tid & 15;                  // 16 groups x 16 rows
    int t = blockIdx.x * 16 + g;
    unsigned* cp = cidx + (long)t * 432;
#pragma unroll
    for (int k = 0; k < 27; k++) {
        int v = snb[(g * 16 + r) * 27 + k];
        cp[k * 16 + r] = (unsigned)((v < 0 ? N : v)) * 512u;
    }
    if (r == 0) kmask[t] = tm[g];
}

// ---------------- blk1 dual: f1|f2 = relu(LN(x@W + b)) ----------------
__global__ __launch_bounds__(256) void blk12_kernel(
    const float* __restrict__ x, unsigned short* cat,
    const unsigned short* __restrict__ Wp,
    const float* __restrict__ b1, const float* __restrict__ g1, const float* __restrict__ be1,
    const float* __restrict__ b2, const float* __restrict__ g2, const float* __restrict__ be2) {
    int tid = threadIdx.x, lane = tid & 63, wv = tid >> 6;
    int l15 = lane & 15, q = lane >> 4;
    long base = ((long)blockIdx.x * 4 + wv) * 16;

    float4_ acc[8];
#pragma unroll
    for (int i = 0; i < 8; i++) acc[i] = (float4_){0.f, 0.f, 0.f, 0.f};

#pragma unroll
    for (int kt = 0; kt < 2; kt++) {
        const float* xp = x + (base + l15) * 64 + kt * 32 + q * 8;
        float4_ f0 = *(const float4_*)xp;
        float4_ f1 = *(const float4_*)(xp + 4);
        short8 as;
        as[0] = (short)f2bf(f0[0]); as[1] = (short)f2bf(f0[1]);
        as[2] = (short)f2bf(f0[2]); as[3] = (short)f2bf(f0[3]);
        as[4] = (short)f2bf(f1[0]); as[5] = (short)f2bf(f1[1]);
        as[6] = (short)f2bf(f1[2]); as[7] = (short)f2bf(f1[3]);
        bf16x8 a = __builtin_bit_cast(bf16x8, as);
        const unsigned short* wp = Wp + (size_t)kt * 8 * 512;
#pragma unroll
        for (int nt = 0; nt < 8; nt++) {
            bf16x8 w = *(const bf16x8*)(wp + nt * 512 + lane * 8);
            acc[nt] = mfma16(a, w, acc[nt]);
        }
    }

    float bc[8], gc[8], bec[8];
#pragma unroll
    for (int nt = 0; nt < 8; nt++) {
        int j = nt * 16 + l15;
        if (j < 64) { bc[nt] = b1[j]; gc[nt] = g1[j]; bec[nt] = be1[j]; }
        else        { bc[nt] = b2[j - 64]; gc[nt] = g2[j - 64]; bec[nt] = be2[j - 64]; }
    }

#pragma unroll
    for (int r = 0; r < 4; r++) {
        long row = base + q * 4 + r;
        float v[8], s0 = 0.f, s1 = 0.f, q0 = 0.f, q1 = 0.f;
#pragma unroll
        for (int nt = 0; nt < 4; nt++) { v[nt] = acc[nt][r] + bc[nt]; s0 += v[nt]; q0 += v[nt] * v[nt]; }
#pragma unroll
        for (int nt = 4; nt < 8; nt++) { v[nt] = acc[nt][r] + bc[nt]; s1 += v[nt]; q1 += v[nt] * v[nt]; }
#pragma unroll
        for (int m = 1; m < 16; m <<= 1) {
            s0 += __shfl_xor(s0, m); q0 += __shfl_xor(q0, m);
            s1 += __shfl_xor(s1, m); q1 += __shfl_xor(q1, m);
        }
        float mu0 = s0 * (1.f / 64), var0 = q0 * (1.f / 64) - mu0 * mu0, inv0 = rsqrtf(var0 + 1e-5f);
        float mu1 = s1 * (1.f / 64), var1 = q1 * (1.f / 64) - mu1 * mu1, inv1 = rsqrtf(var1 + 1e-5f);
        unsigned short* cp = cat + row * 256;
#pragma unroll
        for (int nt = 0; nt < 4; nt++) {
            float y = fmaxf((v[nt] - mu0) * inv0 * gc[nt] + bec[nt], 0.f);
            cp[nt * 16 + l15] = f2bf(y);
        }
#pragma unroll
        for (int nt = 4; nt < 8; nt++) {
            float y = fmaxf((v[nt] - mu1) * inv1 * gc[nt] + bec[nt], 0.f);
            cp[nt * 16 + l15] = f2bf(y);
        }
    }
}

// ---------------- sparse submanifold conv (r3 skeleton + cidx/voff) -----
// r3's proven predicated static-slot pipeline; changes this round:
//   - idx loads from cidx (1 coalesced 64B line per slot, pre-clamped
//     BYTE offsets -> no clamp/mul address math in conv),
//   - gathers: 64-bit base + 32-bit voff (1 VALU add),
//   - LDSW=1 variant stages the whole 54KB weight table in LDS once per
//     block: weight reads leave the vmcnt chain (A/B vs LDSW=0 in-run).
// r8 bugfix: the staging loop must copy 13824 dwords (27648 shorts =
// 55296 bytes), not 6912 dwords — half-staged LDS caused absmax 3.67.
template <int CT, int D, int LDSW>
__global__ __launch_bounds__(256) void conv_kernel(
    unsigned short* cat, const unsigned int* __restrict__ cidx,
    const unsigned int* __restrict__ kmask,
    const unsigned short* __restrict__ Wp,
    const float* __restrict__ bb, const float* __restrict__ gg, const float* __restrict__ bee,
    int in_off, int out_off, int N) {
    __shared__ unsigned short wlds[LDSW ? 27648 : 16];
    int tid = threadIdx.x, lane = tid & 63, wv = tid >> 6;
    int l15 = lane & 15, q = lane >> 4;

    if (LDSW) {                                      // stage 27648 shorts = 13824 dwords
        const unsigned* src = (const unsigned*)Wp;
        unsigned* dst = (unsigned*)wlds;
#pragma unroll
        for (int i = 0; i < 54; i++) dst[i * 256 + tid] = src[i * 256 + tid];
        __syncthreads();
    }

#define WLOAD(KK, CTI, NT)                                                             \
    (LDSW ? *(const bf16x8*)(wlds + ((size_t)(((KK) * CT + (CTI)) * 2 + (NT))) * 512 + lane * 8) \
          : *(const bf16x8*)(Wp   + ((size_t)(((KK) * CT + (CTI)) * 2 + (NT))) * 512 + lane * 8))

    // bijective XCD-chunked swizzle (gridDim.x % 8 == 0)
    int cpx = (int)(gridDim.x >> 3);
    int sb = ((int)blockIdx.x & 7) * cpx + ((int)blockIdx.x >> 3);
    int t = sb * 4 + wv;
    long base = (long)t * 16;

    unsigned m = __builtin_amdgcn_readfirstlane(kmask[t]);

    float4_ acc[2];
    acc[0] = (float4_){0.f, 0.f, 0.f, 0.f};
    acc[1] = (float4_){0.f, 0.f, 0.f, 0.f};

    const char* catb = (const char*)cat + (size_t)in_off * 2 + q * 16;
    const unsigned* cx = cidx + (long)t * 432 + l15;

    bf16x8 f[D + 1][CT];
    bf16x8 wr[3][CT][2];
    unsigned ci[3];

    // ---- prologue (slots 0..D+1), all predicated, all static ----
    unsigned ci0[D + 2];
#pragma unroll
    for (int j = 0; j < D + 2; j++) ci0[j] = (m >> j & 1u) ? cx[j * 16] : 0u;

#pragma unroll
    for (int kk = 0; kk < 2; kk++) {
        if (m >> kk & 1u) {
#pragma unroll
            for (int ct = 0; ct < CT; ct++)
#pragma unroll
                for (int nt = 0; nt < 2; nt++)
                    wr[kk][ct][nt] = WLOAD(kk, ct, nt);
        }
    }

#pragma unroll
    for (int j = 0; j < D; j++) {
        if (m >> j & 1u) {
#pragma unroll
            for (int ct = 0; ct < CT; ct++)
                f[j][ct] = *(const bf16x8*)(catb + (size_t)ci0[j] + ct * 64);
        }
    }
    ci[D % 3] = ci0[D];
    ci[(D + 1) % 3] = ci0[D + 1];

    // ---- main loop: 27 static slots, per-slot scalar predication ----
#pragma unroll
    for (int k = 0; k < 27; k++) {
        if (k + 2 < 27 && (m >> (k + 2) & 1u)) {     // weights for slot k+2
#pragma unroll
            for (int ct = 0; ct < CT; ct++)
#pragma unroll
                for (int nt = 0; nt < 2; nt++)
                    wr[(k + 2) % 3][ct][nt] = WLOAD(k + 2, ct, nt);
        }
        if (k + D < 27 && (m >> (k + D) & 1u)) {     // gathers for slot k+D
            unsigned voff = ci[(k + D) % 3];
#pragma unroll
            for (int ct = 0; ct < CT; ct++)
                f[(k + D) % (D + 1)][ct] = *(const bf16x8*)(catb + (size_t)voff + ct * 64);
        }
        if (k + D + 2 < 27 && (m >> (k + D + 2) & 1u)) {   // idx for k+D+2
            ci[(k + D + 2) % 3] = cx[(k + D + 2) * 16];
        }
        if (m >> k & 1u) {                            // MFMA for slot k
#pragma unroll
            for (int ct = 0; ct < CT; ct++) {
                bf16x8 w0 = wr[k % 3][ct][0];
                bf16x8 w1 = wr[k % 3][ct][1];
                acc[0] = mfma16(f[k % (D + 1)][ct], w0, acc[0]);
                acc[1] = mfma16(f[k % (D + 1)][ct], w1, acc[1]);
            }
        }
    }
#undef WLOAD

    // ---- epilogue: bias + LN(32ch) + relu + store ----
    float b0c = bb[l15], b1c = bb[16 + l15];
    float g0c = gg[l15], g1c = gg[16 + l15];
    float be0c = bee[l15], be1c = bee[16 + l15];

#pragma unroll
    for (int r = 0; r < 4; r++) {
        long row = base + q * 4 + r;
        float v0 = acc[0][r] + b0c;
        float v1 = acc[1][r] + b1c;
        float s = v0 + v1, sq = v0 * v0 + v1 * v1;
#pragma unroll
        for (int mh = 1; mh < 16; mh <<= 1) { s += __shfl_xor(s, mh); sq += __shfl_xor(sq, mh); }
        float mu = s * (1.f / 32), var = sq * (1.f / 32) - mu * mu, inv = rsqrtf(var + 1e-5f);
        float y0 = fmaxf((v0 - mu) * inv * g0c + be0c, 0.f);
        float y1 = fmaxf((v1 - mu) * inv * g1c + be1c, 0.f);
        unsigned short* cp = cat + row * 256 + out_off;
        cp[l15] = f2bf(y0);
        cp[16 + l15] = f2bf(y1);
    }
}

// ---------------- final blk1: out = relu(LN(cat@W7 + b7)) ----------------
__global__ __launch_bounds__(256) void blk7_kernel(
    const unsigned short* __restrict__ cat, const unsigned short* __restrict__ Wp,
    const float* __restrict__ b, const float* __restrict__ g, const float* __restrict__ be,
    float* __restrict__ out) {
    int tid = threadIdx.x, lane = tid & 63, wv = tid >> 6;
    int l15 = lane & 15, q = lane >> 4;
    long base = ((long)blockIdx.x * 4 + wv) * 16;

    float4_ acc[4];
#pragma unroll
    for (int i = 0; i < 4; i++) acc[i] = (float4_){0.f, 0.f, 0.f, 0.f};

#pragma unroll
    for (int kt = 0; kt < 8; kt++) {
        bf16x8 a = *(const bf16x8*)(cat + (base + l15) * 256 + kt * 32 + q * 8);
        const unsigned short* wp = Wp + (size_t)kt * 4 * 512;
#pragma unroll
        for (int nt = 0; nt < 4; nt++) {
            bf16x8 w = *(const bf16x8*)(wp + nt * 512 + lane * 8);
            acc[nt] = mfma16(a, w, acc[nt]);
        }
    }

    float bc[4], gc[4], bec[4];
#pragma unroll
    for (int nt = 0; nt < 4; nt++) {
        int j = nt * 16 + l15;
        bc[nt] = b[j]; gc[nt] = g[j]; bec[nt] = be[j];
    }

#pragma unroll
    for (int r = 0; r < 4; r++) {
        long row = base + q * 4 + r;
        float v[4], s = 0.f, sq = 0.f;
#pragma unroll
        for (int nt = 0; nt < 4; nt++) { v[nt] = acc[nt][r] + bc[nt]; s += v[nt]; sq += v[nt] * v[nt]; }
#pragma unroll
        for (int m = 1; m < 16; m <<= 1) { s += __shfl_xor(s, m); sq += __shfl_xor(sq, m); }
        float mu = s * (1.f / 64), var = sq * (1.f / 64) - mu * mu, inv = rsqrtf(var + 1e-5f);
#pragma unroll
        for (int nt = 0; nt < 4; nt++) {
            float y = fmaxf((v[nt] - mu) * inv * gc[nt] + bec[nt], 0.f);
            out[row * 64 + nt * 16 + l15] = y;
        }
    }
}

extern "C" void kernel_launch(void* const* d_in, const int* in_sizes, int n_in,
                              void* d_out, int out_size, void* d_ws, size_t ws_size,
                              hipStream_t stream) {
    const int N = in_sizes[0] / 64;   // 262144

    const float* x   = (const float*)d_in[0];
    const int*   nbr = (const int*)d_in[1];
    const float* W1 = (const float*)d_in[2];
    const float* b1 = (const float*)d_in[3];
    const float* g1 = (const float*)d_in[4];
    const float* be1 = (const float*)d_in[5];
    const float* W2 = (const float*)d_in[6];
    const float* b2 = (const float*)d_in[7];
    const float* g2 = (const float*)d_in[8];
    const float* be2 = (const float*)d_in[9];
    const float* W3 = (const float*)d_in[10];
    const float* b3 = (const float*)d_in[11];
    const float* g3 = (const float*)d_in[12];
    const float* be3 = (const float*)d_in[13];
    const float* W4 = (const float*)d_in[14];
    const float* b4 = (const float*)d_in[15];
    const float* g4 = (const float*)d_in[16];
    const float* be4 = (const float*)d_in[17];
    const float* W5 = (const float*)d_in[18];
    const float* b5 = (const float*)d_in[19];
    const float* g5 = (const float*)d_in[20];
    const float* be5 = (const float*)d_in[21];
    const float* W6 = (const float*)d_in[22];
    const float* b6 = (const float*)d_in[23];
    const float* g6 = (const float*)d_in[24];
    const float* be6 = (const float*)d_in[25];
    const float* W7 = (const float*)d_in[26];
    const float* b7 = (const float*)d_in[27];
    const float* g7 = (const float*)d_in[28];
    const float* be7 = (const float*)d_in[29];

    unsigned short* ws   = (unsigned short*)d_ws;
    unsigned short* cat  = ws;                               // (N+1)*256 bf16
    unsigned short* Wp12 = cat + (size_t)(N + 1) * 256;      // 8192
    unsigned short* Wp3  = Wp12 + 8192;                      // 27*2*2*512 = 55296
    unsigned short* Wp4  = Wp3 + 55296;                      // 27*1*2*512 = 27648
    unsigned short* Wp5  = Wp4 + 27648;
    unsigned short* Wp6  = Wp5 + 27648;
    unsigned short* Wp7  = Wp6 + 27648;                      // 8*4*512 = 16384
    unsigned int*   kmask = (unsigned int*)(Wp7 + 16384);    // N/16 uints
    unsigned int*   cidx  = kmask + N / 16;                  // N/16 * 432 uints

    pack_all_kernel<<<637, 256, 0, stream>>>(W1, W2, W3, W4, W5, W6, W7,
                                             cat, Wp12, Wp3, Wp4, Wp5, Wp6, Wp7, N);
    plan_kernel<<<N / 256, 256, 0, stream>>>(nbr, kmask, cidx, N);

    blk12_kernel<<<N / 64, 256, 0, stream>>>(x, cat, Wp12, b1, g1, be1, b2, g2, be2);
    conv_kernel<2, 3, 0><<<N / 64, 256, 0, stream>>>(cat, cidx, kmask, Wp3, b3, g3, be3, 64, 128, N);
    conv_kernel<1, 4, 1><<<N / 64, 256, 0, stream>>>(cat, cidx, kmask, Wp4, b4, g4, be4, 128, 160, N);
    conv_kernel<1, 4, 0><<<N / 64, 256, 0, stream>>>(cat, cidx, kmask, Wp5, b5, g5, be5, 160, 192, N);
    conv_kernel<1, 4, 0><<<N / 64, 256, 0, stream>>>(cat, cidx, kmask, Wp6, b6, g6, be6, 192, 224, N);
    blk7_kernel<<<N / 64, 256, 0, stream>>>(cat, Wp7, b7, g7, be7, (float*)d_out);
}

// Round 10
// 434.557 us; speedup vs baseline: 1.2070x; 1.2050x over previous
//
#include <hip/hip_runtime.h>

typedef __attribute__((ext_vector_type(4))) float  float4_;
typedef __attribute__((ext_vector_type(8))) short  short8;
typedef __attribute__((ext_vector_type(8))) __bf16 bf16x8;
typedef __attribute__((ext_vector_type(4))) unsigned uint4_;

__device__ inline unsigned short f2bf(float f) {
    unsigned u = __builtin_bit_cast(unsigned, f);
    u += 0x7FFFu + ((u >> 16) & 1u);          // round-to-nearest-even
    return (unsigned short)(u >> 16);
}

__device__ inline float4_ mfma16(bf16x8 a, bf16x8 b, float4_ c) {
    return __builtin_amdgcn_mfma_f32_16x16x32_bf16(a, b, c, 0, 0, 0);
}

// ---------------- one merged setup kernel (28 slots: slot 27 all-zero) ---
// packs all weights into B-fragment order + zeroes sentinel row cat[N].
// frag f = (k*ctn + ct)*ntn + nt ; elem = lane*8 + t
// value = W[k][ct*32 + (lane>>4)*8 + t][nt*16 + (lane&15)]
__device__ inline void packW_one(const float* __restrict__ src, unsigned short* __restrict__ dst,
                                 int cin, int cout, int e) {
    int f = e >> 9, i = e & 511, lane = i >> 3, t = i & 7;
    int ntn = cout >> 4, ctn = cin >> 5;
    int nt = f % ntn;
    int rest = f / ntn;
    int ct = rest % ctn;
    int k = rest / ctn;
    int c = ct * 32 + (lane >> 4) * 8 + t;
    int j = nt * 16 + (lane & 15);
    dst[e] = f2bf(src[(k * cin + c) * cout + j]);
}

__global__ void pack_all_kernel(
    const float* __restrict__ W1, const float* __restrict__ W2,
    const float* __restrict__ W3, const float* __restrict__ W4,
    const float* __restrict__ W5, const float* __restrict__ W6,
    const float* __restrict__ W7,
    unsigned short* cat, unsigned short* Wp12, unsigned short* Wp3,
    unsigned short* Wp4, unsigned short* Wp5, unsigned short* Wp6,
    unsigned short* Wp7, int N) {
    int e = blockIdx.x * 256 + threadIdx.x;
    if (e < 8192) {                                  // W1|W2 -> (64,128)
        int f = e >> 9, i = e & 511, lane = i >> 3, t = i & 7;
        int nt = f & 7, ct = f >> 3;
        int c = ct * 32 + (lane >> 4) * 8 + t;
        int j = nt * 16 + (lane & 15);
        float v = (j < 64) ? W1[c * 64 + j] : W2[c * 64 + (j - 64)];
        Wp12[e] = f2bf(v);
        return;
    }
    e -= 8192;
    if (e < 57344) { if (e < 55296) packW_one(W3, Wp3, 64, 32, e); else Wp3[e] = 0; return; }
    e -= 57344;
    if (e < 28672) { if (e < 27648) packW_one(W4, Wp4, 32, 32, e); else Wp4[e] = 0; return; }
    e -= 28672;
    if (e < 28672) { if (e < 27648) packW_one(W5, Wp5, 32, 32, e); else Wp5[e] = 0; return; }
    e -= 28672;
    if (e < 28672) { if (e < 27648) packW_one(W6, Wp6, 32, 32, e); else Wp6[e] = 0; return; }
    e -= 28672;
    if (e < 16384) { packW_one(W7, Wp7, 256, 64, e); return; }
    e -= 16384;
    if (e < 128) ((unsigned*)(cat + (size_t)N * 256))[e] = 0;   // sentinel row
}

// ---------------- plan kernel v5: COMPACTED slot stream per tile ---------
// Per 16-row tile t (coalesced nbr read via LDS):
//   kmask[t]          union mask (conv only needs popcount)
//   cidx[t][j][r]     j-th ACTIVE tap's clamped BYTE offset for row r
//                     (j in ascending-k order; j >= c -> sentinel N*512)
//   ktab[t][j]        j-th active tap id (byte); j >= c -> 27 (zero W block)
__global__ __launch_bounds__(256) void plan_kernel(const int* __restrict__ nbr,
                                                   unsigned int* __restrict__ kmask,
                                                   unsigned int* __restrict__ cidx,
                                                   unsigned char* __restrict__ ktab, int N) {
    __shared__ int snb[6912];                        // 256 rows * 27 taps
    __shared__ unsigned tm[16];
    int tid = threadIdx.x;
    if (tid < 16) tm[tid] = 0u;
    __syncthreads();
    long base = (long)blockIdx.x * 6912;
#pragma unroll
    for (int i = 0; i < 27; i++) {
        int j = i * 256 + tid;
        int v = nbr[base + j];
        snb[j] = v;
        if (v >= 0) {
            unsigned r = (unsigned)j / 27u;          // local row 0..255
            unsigned k = (unsigned)j - r * 27u;
            atomicOr(&tm[r >> 4], 1u << k);
        }
    }
    __syncthreads();
    int g = tid >> 4, r = tid & 15;                  // 16 groups x 16 rows
    unsigned m = tm[g];
    int t = blockIdx.x * 16 + g;
    unsigned* cp = cidx + (long)t * 448;
    int j = 0;
#pragma unroll
    for (int k = 0; k < 27; k++) {
        if (m >> k & 1u) {
            int v = snb[(g * 16 + r) * 27 + k];
            cp[j * 16 + r] = (unsigned)(v < 0 ? N : v) * 512u;
            j++;
        }
    }
    for (; j < 28; j++) cp[j * 16 + r] = (unsigned)N * 512u;
    if (r == 0) {
        kmask[t] = m;
        unsigned char* kt = ktab + (long)t * 32;
        int jj = 0;
#pragma unroll
        for (int k = 0; k < 27; k++)
            if (m >> k & 1u) kt[jj++] = (unsigned char)k;
        for (; jj < 32; jj++) kt[jj] = 27;
    }
}

// ---------------- blk1 dual: f1|f2 = relu(LN(x@W + b)) ----------------
__global__ __launch_bounds__(256) void blk12_kernel(
    const float* __restrict__ x, unsigned short* cat,
    const unsigned short* __restrict__ Wp,
    const float* __restrict__ b1, const float* __restrict__ g1, const float* __restrict__ be1,
    const float* __restrict__ b2, const float* __restrict__ g2, const float* __restrict__ be2) {
    int tid = threadIdx.x, lane = tid & 63, wv = tid >> 6;
    int l15 = lane & 15, q = lane >> 4;
    long base = ((long)blockIdx.x * 4 + wv) * 16;

    float4_ acc[8];
#pragma unroll
    for (int i = 0; i < 8; i++) acc[i] = (float4_){0.f, 0.f, 0.f, 0.f};

#pragma unroll
    for (int kt = 0; kt < 2; kt++) {
        const float* xp = x + (base + l15) * 64 + kt * 32 + q * 8;
        float4_ f0 = *(const float4_*)xp;
        float4_ f1 = *(const float4_*)(xp + 4);
        short8 as;
        as[0] = (short)f2bf(f0[0]); as[1] = (short)f2bf(f0[1]);
        as[2] = (short)f2bf(f0[2]); as[3] = (short)f2bf(f0[3]);
        as[4] = (short)f2bf(f1[0]); as[5] = (short)f2bf(f1[1]);
        as[6] = (short)f2bf(f1[2]); as[7] = (short)f2bf(f1[3]);
        bf16x8 a = __builtin_bit_cast(bf16x8, as);
        const unsigned short* wp = Wp + (size_t)kt * 8 * 512;
#pragma unroll
        for (int nt = 0; nt < 8; nt++) {
            bf16x8 w = *(const bf16x8*)(wp + nt * 512 + lane * 8);
            acc[nt] = mfma16(a, w, acc[nt]);
        }
    }

    float bc[8], gc[8], bec[8];
#pragma unroll
    for (int nt = 0; nt < 8; nt++) {
        int j = nt * 16 + l15;
        if (j < 64) { bc[nt] = b1[j]; gc[nt] = g1[j]; bec[nt] = be1[j]; }
        else        { bc[nt] = b2[j - 64]; gc[nt] = g2[j - 64]; bec[nt] = be2[j - 64]; }
    }

#pragma unroll
    for (int r = 0; r < 4; r++) {
        long row = base + q * 4 + r;
        float v[8], s0 = 0.f, s1 = 0.f, q0 = 0.f, q1 = 0.f;
#pragma unroll
        for (int nt = 0; nt < 4; nt++) { v[nt] = acc[nt][r] + bc[nt]; s0 += v[nt]; q0 += v[nt] * v[nt]; }
#pragma unroll
        for (int nt = 4; nt < 8; nt++) { v[nt] = acc[nt][r] + bc[nt]; s1 += v[nt]; q1 += v[nt] * v[nt]; }
#pragma unroll
        for (int m = 1; m < 16; m <<= 1) {
            s0 += __shfl_xor(s0, m); q0 += __shfl_xor(q0, m);
            s1 += __shfl_xor(s1, m); q1 += __shfl_xor(q1, m);
        }
        float mu0 = s0 * (1.f / 64), var0 = q0 * (1.f / 64) - mu0 * mu0, inv0 = rsqrtf(var0 + 1e-5f);
        float mu1 = s1 * (1.f / 64), var1 = q1 * (1.f / 64) - mu1 * mu1, inv1 = rsqrtf(var1 + 1e-5f);
        unsigned short* cp = cat + row * 256;
#pragma unroll
        for (int nt = 0; nt < 4; nt++) {
            float y = fmaxf((v[nt] - mu0) * inv0 * gc[nt] + bec[nt], 0.f);
            cp[nt * 16 + l15] = f2bf(y);
        }
#pragma unroll
        for (int nt = 4; nt < 8; nt++) {
            float y = fmaxf((v[nt] - mu1) * inv1 * gc[nt] + bec[nt], 0.f);
            cp[nt * 16 + l15] = f2bf(y);
        }
    }
}

// ---------------- sparse conv: branchless unrolled core over NS slots ----
// r9 lesson: per-slot scalar branches cost 1.5x per slot (conservative
// vmcnt drains at joins — r6's branchless dense ran 3.7 vs 5.5 us/slot).
// v10: compacted slot stream (plan v5) consumed by a fully-unrolled,
// branch-FREE r0-style ring pipeline over NS = 4*ceil(c/4) static slots;
// one wave-uniform switch picks NS. Sentinel slots (j >= c) read the zero
// row and the all-zero weight block 27 -> contribute exactly 0.
template <int CT, int D, int NS>
__device__ __forceinline__ void conv_core(
    float4_ acc[2], const char* catb, const unsigned* cx,
    const unsigned* kt8, const unsigned short* wl) {
    bf16x8 f[D + 1][CT];
    bf16x8 wr[3][CT][2];
    unsigned cv[3];

#define KB(k) ((kt8[(k) >> 2] >> (((k) & 3) * 8)) & 0xFFu)

    unsigned cv0[D + 2];
#pragma unroll
    for (int j = 0; j < D + 2; j++) cv0[j] = cx[j * 16];

#pragma unroll
    for (int kk = 0; kk < 2; kk++) {
        unsigned wo = KB(kk) * (CT * 1024u);
#pragma unroll
        for (int ct = 0; ct < CT; ct++)
#pragma unroll
            for (int nt = 0; nt < 2; nt++)
                wr[kk][ct][nt] = *(const bf16x8*)(wl + wo + (ct * 2 + nt) * 512);
    }

#pragma unroll
    for (int j = 0; j < D; j++) {
#pragma unroll
        for (int ct = 0; ct < CT; ct++)
            f[j][ct] = *(const bf16x8*)(catb + (size_t)cv0[j] + ct * 64);
    }
    cv[D % 3] = cv0[D];
    cv[(D + 1) % 3] = cv0[D + 1];

#pragma unroll
    for (int k = 0; k < NS; k++) {
        if (k + 2 < NS) {                            // weights for slot k+2
            unsigned wo = KB(k + 2) * (CT * 1024u);
#pragma unroll
            for (int ct = 0; ct < CT; ct++)
#pragma unroll
                for (int nt = 0; nt < 2; nt++)
                    wr[(k + 2) % 3][ct][nt] = *(const bf16x8*)(wl + wo + (ct * 2 + nt) * 512);
        }
        if (k + D < NS) {                            // gathers for slot k+D
            unsigned voff = cv[(k + D) % 3];
#pragma unroll
            for (int ct = 0; ct < CT; ct++)
                f[(k + D) % (D + 1)][ct] = *(const bf16x8*)(catb + (size_t)voff + ct * 64);
        }
        if (k + D + 2 < NS) cv[(k + D + 2) % 3] = cx[(k + D + 2) * 16];
#pragma unroll
        for (int ct = 0; ct < CT; ct++) {            // MFMA for slot k
            acc[0] = mfma16(f[k % (D + 1)][ct], wr[k % 3][ct][0], acc[0]);
            acc[1] = mfma16(f[k % (D + 1)][ct], wr[k % 3][ct][1], acc[1]);
        }
    }
#undef KB
}

template <int CT, int D>
__global__ __launch_bounds__(256) void conv_kernel(
    unsigned short* cat, const unsigned int* __restrict__ cidx,
    const unsigned char* __restrict__ ktab,
    const unsigned int* __restrict__ kmask,
    const unsigned short* __restrict__ Wp,
    const float* __restrict__ bb, const float* __restrict__ gg, const float* __restrict__ bee,
    int in_off, int out_off, int N) {
    int tid = threadIdx.x, lane = tid & 63, wv = tid >> 6;
    int l15 = lane & 15, q = lane >> 4;

    // bijective XCD-chunked swizzle (gridDim.x % 8 == 0)
    int cpx = (int)(gridDim.x >> 3);
    int sb = ((int)blockIdx.x & 7) * cpx + ((int)blockIdx.x >> 3);
    int t = sb * 4 + wv;
    long base = (long)t * 16;

    unsigned m = __builtin_amdgcn_readfirstlane(kmask[t]);
    int trips = (__popc(m) + 3) >> 2;                // 1..7 (self tap => c>=1)

    const char* catb = (const char*)cat + (size_t)in_off * 2 + q * 16;
    const unsigned* cx = cidx + (long)t * 448 + l15;
    const unsigned short* wl = Wp + lane * 8;

    uint4_ kv0 = *(const uint4_*)(ktab + (long)t * 32);
    uint4_ kv1 = *(const uint4_*)(ktab + (long)t * 32 + 16);
    unsigned kt8[8] = {kv0[0], kv0[1], kv0[2], kv0[3], kv1[0], kv1[1], kv1[2], kv1[3]};

    float4_ acc[2];
    acc[0] = (float4_){0.f, 0.f, 0.f, 0.f};
    acc[1] = (float4_){0.f, 0.f, 0.f, 0.f};

    switch (trips) {
        case 1: conv_core<CT, D, 4>(acc, catb, cx, kt8, wl); break;
        case 2: conv_core<CT, D, 8>(acc, catb, cx, kt8, wl); break;
        case 3: conv_core<CT, D, 12>(acc, catb, cx, kt8, wl); break;
        case 4: conv_core<CT, D, 16>(acc, catb, cx, kt8, wl); break;
        case 5: conv_core<CT, D, 20>(acc, catb, cx, kt8, wl); break;
        case 6: conv_core<CT, D, 24>(acc, catb, cx, kt8, wl); break;
        default: conv_core<CT, D, 28>(acc, catb, cx, kt8, wl); break;
    }

    // ---- epilogue: bias + LN(32ch) + relu + store ----
    float b0c = bb[l15], b1c = bb[16 + l15];
    float g0c = gg[l15], g1c = gg[16 + l15];
    float be0c = bee[l15], be1c = bee[16 + l15];

#pragma unroll
    for (int r = 0; r < 4; r++) {
        long row = base + q * 4 + r;
        float v0 = acc[0][r] + b0c;
        float v1 = acc[1][r] + b1c;
        float s = v0 + v1, sq = v0 * v0 + v1 * v1;
#pragma unroll
        for (int mh = 1; mh < 16; mh <<= 1) { s += __shfl_xor(s, mh); sq += __shfl_xor(sq, mh); }
        float mu = s * (1.f / 32), var = sq * (1.f / 32) - mu * mu, inv = rsqrtf(var + 1e-5f);
        float y0 = fmaxf((v0 - mu) * inv * g0c + be0c, 0.f);
        float y1 = fmaxf((v1 - mu) * inv * g1c + be1c, 0.f);
        unsigned short* cp = cat + row * 256 + out_off;
        cp[l15] = f2bf(y0);
        cp[16 + l15] = f2bf(y1);
    }
}

// ---------------- final blk1: out = relu(LN(cat@W7 + b7)) ----------------
__global__ __launch_bounds__(256) void blk7_kernel(
    const unsigned short* __restrict__ cat, const unsigned short* __restrict__ Wp,
    const float* __restrict__ b, const float* __restrict__ g, const float* __restrict__ be,
    float* __restrict__ out) {
    int tid = threadIdx.x, lane = tid & 63, wv = tid >> 6;
    int l15 = lane & 15, q = lane >> 4;
    long base = ((long)blockIdx.x * 4 + wv) * 16;

    float4_ acc[4];
#pragma unroll
    for (int i = 0; i < 4; i++) acc[i] = (float4_){0.f, 0.f, 0.f, 0.f};

#pragma unroll
    for (int kt = 0; kt < 8; kt++) {
        bf16x8 a = *(const bf16x8*)(cat + (base + l15) * 256 + kt * 32 + q * 8);
        const unsigned short* wp = Wp + (size_t)kt * 4 * 512;
#pragma unroll
        for (int nt = 0; nt < 4; nt++) {
            bf16x8 w = *(const bf16x8*)(wp + nt * 512 + lane * 8);
            acc[nt] = mfma16(a, w, acc[nt]);
        }
    }

    float bc[4], gc[4], bec[4];
#pragma unroll
    for (int nt = 0; nt < 4; nt++) {
        int j = nt * 16 + l15;
        bc[nt] = b[j]; gc[nt] = g[j]; bec[nt] = be[j];
    }

#pragma unroll
    for (int r = 0; r < 4; r++) {
        long row = base + q * 4 + r;
        float v[4], s = 0.f, sq = 0.f;
#pragma unroll
        for (int nt = 0; nt < 4; nt++) { v[nt] = acc[nt][r] + bc[nt]; s += v[nt]; sq += v[nt] * v[nt]; }
#pragma unroll
        for (int m = 1; m < 16; m <<= 1) { s += __shfl_xor(s, m); sq += __shfl_xor(sq, m); }
        float mu = s * (1.f / 64), var = sq * (1.f / 64) - mu * mu, inv = rsqrtf(var + 1e-5f);
#pragma unroll
        for (int nt = 0; nt < 4; nt++) {
            float y = fmaxf((v[nt] - mu) * inv * gc[nt] + bec[nt], 0.f);
            out[row * 64 + nt * 16 + l15] = y;
        }
    }
}

extern "C" void kernel_launch(void* const* d_in, const int* in_sizes, int n_in,
                              void* d_out, int out_size, void* d_ws, size_t ws_size,
                              hipStream_t stream) {
    const int N = in_sizes[0] / 64;   // 262144

    const float* x   = (const float*)d_in[0];
    const int*   nbr = (const int*)d_in[1];
    const float* W1 = (const float*)d_in[2];
    const float* b1 = (const float*)d_in[3];
    const float* g1 = (const float*)d_in[4];
    const float* be1 = (const float*)d_in[5];
    const float* W2 = (const float*)d_in[6];
    const float* b2 = (const float*)d_in[7];
    const float* g2 = (const float*)d_in[8];
    const float* be2 = (const float*)d_in[9];
    const float* W3 = (const float*)d_in[10];
    const float* b3 = (const float*)d_in[11];
    const float* g3 = (const float*)d_in[12];
    const float* be3 = (const float*)d_in[13];
    const float* W4 = (const float*)d_in[14];
    const float* b4 = (const float*)d_in[15];
    const float* g4 = (const float*)d_in[16];
    const float* be4 = (const float*)d_in[17];
    const float* W5 = (const float*)d_in[18];
    const float* b5 = (const float*)d_in[19];
    const float* g5 = (const float*)d_in[20];
    const float* be5 = (const float*)d_in[21];
    const float* W6 = (const float*)d_in[22];
    const float* b6 = (const float*)d_in[23];
    const float* g6 = (const float*)d_in[24];
    const float* be6 = (const float*)d_in[25];
    const float* W7 = (const float*)d_in[26];
    const float* b7 = (const float*)d_in[27];
    const float* g7 = (const float*)d_in[28];
    const float* be7 = (const float*)d_in[29];

    unsigned short* ws   = (unsigned short*)d_ws;
    unsigned short* cat  = ws;                               // (N+1)*256 bf16
    unsigned short* Wp12 = cat + (size_t)(N + 1) * 256;      // 8192
    unsigned short* Wp3  = Wp12 + 8192;                      // 28*2*2*512 = 57344 (slot 27 zero)
    unsigned short* Wp4  = Wp3 + 57344;                      // 28*1*2*512 = 28672
    unsigned short* Wp5  = Wp4 + 28672;
    unsigned short* Wp6  = Wp5 + 28672;
    unsigned short* Wp7  = Wp6 + 28672;                      // 8*4*512 = 16384
    unsigned int*   kmask = (unsigned int*)(Wp7 + 16384);    // N/16 uints
    unsigned int*   cidx  = kmask + N / 16;                  // N/16 * 448 uints
    unsigned char*  ktab  = (unsigned char*)(cidx + (size_t)(N / 16) * 448);  // N/16 * 32 B

    pack_all_kernel<<<657, 256, 0, stream>>>(W1, W2, W3, W4, W5, W6, W7,
                                             cat, Wp12, Wp3, Wp4, Wp5, Wp6, Wp7, N);
    plan_kernel<<<N / 256, 256, 0, stream>>>(nbr, kmask, cidx, ktab, N);

    blk12_kernel<<<N / 64, 256, 0, stream>>>(x, cat, Wp12, b1, g1, be1, b2, g2, be2);
    conv_kernel<2, 3><<<N / 64, 256, 0, stream>>>(cat, cidx, ktab, kmask, Wp3, b3, g3, be3, 64, 128, N);
    conv_kernel<1, 4><<<N / 64, 256, 0, stream>>>(cat, cidx, ktab, kmask, Wp4, b4, g4, be4, 128, 160, N);
    conv_kernel<1, 4><<<N / 64, 256, 0, stream>>>(cat, cidx, ktab, kmask, Wp5, b5, g5, be5, 160, 192, N);
    conv_kernel<1, 4><<<N / 64, 256, 0, stream>>>(cat, cidx, ktab, kmask, Wp6, b6, g6, be6, 192, 224, N);
    blk7_kernel<<<N / 64, 256, 0, stream>>>(cat, Wp7, b7, g7, be7, (float*)d_out);
}